// Round 4
// baseline (590.039 us; speedup 1.0000x reference)
//
#include <hip/hip_runtime.h>

#define N_NODES 100000
#define N_EDGES 3200000
#define D 256

#define NBKT 391           // row-buckets of 256 rows each (391*256 = 100096)
#define BCAP 9216          // entries per bucket region; mean 8184, ~11 sigma margin
#define P1_BLOCKS 782      // ceil(3.2M / 4096 edges per block)
#define GEMM_BLOCKS 1563   // 6250 waves (16 rows each) / 4 per block
#define CVT_BLOCKS 64      // 65536 W elems / (256*4)

using bf16x8 = __attribute__((ext_vector_type(8))) short;
using f32x4  = __attribute__((ext_vector_type(4))) float;
using i32x4  = __attribute__((ext_vector_type(4))) int;
using i32x2  = __attribute__((ext_vector_type(2))) int;

__device__ inline float bf2f(unsigned short b) {
    union { unsigned u; float f; } v; v.u = ((unsigned)b) << 16; return v.f;
}
__device__ inline unsigned short f2bf(float f) {
    union { float f; unsigned u; } v; v.f = f;
    unsigned u = v.u;
    u += 0x7FFFu + ((u >> 16) & 1u);   // round-to-nearest-even
    return (unsigned short)(u >> 16);
}

// ---- prep: [0,64) convert W fp32->bf16; [64,66) init bucket_next ----
__global__ __launch_bounds__(256) void prep(const float* __restrict__ W,
                                            unsigned short* __restrict__ wb,
                                            int* __restrict__ bucket_next) {
    int bid = blockIdx.x;
    if (bid < CVT_BLOCKS) {
        int i = (bid * 256 + threadIdx.x) * 4;
        float4 f = *(const float4*)(W + i);
        ushort4 o;
        o.x = f2bf(f.x); o.y = f2bf(f.y); o.z = f2bf(f.z); o.w = f2bf(f.w);
        *(ushort4*)(wb + i) = o;
    } else {
        int t = (bid - CVT_BLOCKS) * 256 + threadIdx.x;
        if (t < NBKT) bucket_next[t] = t * BCAP;
    }
}

// ---- fused: GEMM (MFMA) || edge partition into row-buckets ----
// Partition role: per-edge ranking via LDS atomics (CU-local); only ~391
// global atomics per block for space reservation (42x fewer memory-side RMWs
// than per-edge atomics, which measured ~20/cycle device-wide).
__global__ __launch_bounds__(256) void gemm_part(
    const float* __restrict__ x,            // [N_NODES, 256] fp32
    const unsigned short* __restrict__ wb,  // [256, 256] bf16
    unsigned short* __restrict__ sb,        // [N_NODES, 256] bf16 out
    const i32x4* __restrict__ erow4,
    const i32x4* __restrict__ ecol4,
    const f32x4* __restrict__ eval4,
    int* __restrict__ bucket_next,          // [NBKT], pre-set to b*BCAP
    i32x2* __restrict__ bkt)                // [NBKT*BCAP] partitioned edges
{
    __shared__ int h_cnt[NBKT];
    __shared__ int h_base[NBKT];
    int bid = blockIdx.x;
    int r3 = bid % 3, g3 = bid / 3;
    if (r3 == 0) {
        // ---------- partition role: p in [0, 782) ----------
        int p = g3;
        int tid = threadIdx.x;
        for (int i = tid; i < NBKT; i += 256) h_cnt[i] = 0;
        __syncthreads();
        int e0 = p * 4096;
        int jmax = (N_EDGES - e0) >> 10; if (jmax > 4) jmax = 4;  // 1024-edge quarters
        int w0[4][4], w1[4][4], bs[4][4];
#pragma unroll
        for (int j = 0; j < 4; ++j) {
            if (j < jmax) {
                int q = p * 1024 + j * 256 + tid;          // i32x4 index
                i32x4 r4 = __builtin_nontemporal_load(erow4 + q);
                i32x4 c4 = __builtin_nontemporal_load(ecol4 + q);
                f32x4 v4 = __builtin_nontemporal_load(eval4 + q);
#pragma unroll
                for (int k = 0; k < 4; ++k) {
                    int row = r4[k];
                    int b   = row >> 8;
                    int rl  = row & 255;
                    int slot = atomicAdd(&h_cnt[b], 1);    // LDS atomic, returning
                    w0[j][k] = c4[k] | (rl << 24);
                    w1[j][k] = __float_as_int(v4[k]);
                    bs[j][k] = (b << 14) | slot;           // slot < 4096 fits 14b
                }
            }
        }
        __syncthreads();
        for (int i = tid; i < NBKT; i += 256)
            h_base[i] = atomicAdd(&bucket_next[i], h_cnt[i]);  // global, ~391/block
        __syncthreads();
#pragma unroll
        for (int j = 0; j < 4; ++j) {
            if (j < jmax) {
#pragma unroll
                for (int k = 0; k < 4; ++k) {
                    int b    = bs[j][k] >> 14;
                    int slot = bs[j][k] & 16383;
                    int dst  = h_base[b] + slot;
                    if (dst < (b + 1) * BCAP) {            // ~11-sigma safety clamp
                        i32x2 o; o[0] = w0[j][k]; o[1] = w1[j][k];
                        bkt[dst] = o;
                    }
                }
            }
        }
        return;
    }
    // ---------- GEMM role: g = 2*g3 + (r3-1) in [0, 1564) ----------
    int g = 2 * g3 + (r3 - 1);
    int wave = g * 4 + (int)(threadIdx.x >> 6);
    int m0 = wave << 4;
    if (m0 >= N_NODES) return;
    int lane = threadIdx.x & 63;
    int quad = lane >> 4;
    int r16  = lane & 15;

    const f32x4* arow = (const f32x4*)(x + (size_t)(m0 + r16) * D + quad * 8);
    const unsigned short* bbase = wb + (size_t)r16 * D + quad * 8;

    f32x4 acc[16];
#pragma unroll
    for (int t = 0; t < 16; ++t) acc[t] = (f32x4){0.f, 0.f, 0.f, 0.f};

    for (int k0 = 0; k0 < D; k0 += 32) {
        f32x4 fa0 = __builtin_nontemporal_load(arow + (k0 >> 2));
        f32x4 fa1 = __builtin_nontemporal_load(arow + (k0 >> 2) + 1);
        bf16x8 a;
        a[0] = (short)f2bf(fa0[0]); a[1] = (short)f2bf(fa0[1]);
        a[2] = (short)f2bf(fa0[2]); a[3] = (short)f2bf(fa0[3]);
        a[4] = (short)f2bf(fa1[0]); a[5] = (short)f2bf(fa1[1]);
        a[6] = (short)f2bf(fa1[2]); a[7] = (short)f2bf(fa1[3]);
#pragma unroll
        for (int t = 0; t < 16; ++t) {
            bf16x8 b = *(const bf16x8*)(bbase + (size_t)t * 16 * D + k0);
            // swapped operands: lane holds 4 consecutive channels of one node
            acc[t] = __builtin_amdgcn_mfma_f32_16x16x32_bf16(b, a, acc[t], 0, 0, 0);
        }
    }

#pragma unroll
    for (int t = 0; t < 16; ++t) {
        ushort4 o;
        o.x = f2bf(acc[t][0]); o.y = f2bf(acc[t][1]);
        o.z = f2bf(acc[t][2]); o.w = f2bf(acc[t][3]);
        *(ushort4*)(sb + (size_t)(m0 + r16) * D + t * 16 + quad * 4) = o;
    }
}

// ---- pass2: group each bucket by (row, col-chunk), in place ----
// key = (rl<<5) | (col>>12): within each row, edges come out sorted by
// 4096-col chunk (2 MB of sb). Concurrent spmm waves then sweep col-space
// monotonically -> the active sb slice stays L2-resident (fetch floor
// 8 XCD x 51.2 MB ~ 410 MB vs 783 MB measured for random order).
__global__ __launch_bounds__(1024) void build_csr(
    const int* __restrict__ bucket_next,
    i32x2* __restrict__ bkt,               // in: partitioned, out: grouped
    int* __restrict__ rowptr, int* __restrict__ cntout)
{
    __shared__ int cntp[4096];             // 8192 keys, packed 2x16-bit
    __shared__ unsigned short scn16[8192]; // exclusive offsets (<= 9216)
    __shared__ int ts[1024];
    int b = blockIdx.x;
    int tid = threadIdx.x;
    int base = b * BCAP;
    int ne = bucket_next[b] - base; if (ne > BCAP) ne = BCAP;

    for (int i = tid; i < 4096; i += 1024) cntp[i] = 0;
    __syncthreads();

    int w0[9], w1[9], sp[9];
#pragma unroll
    for (int j = 0; j < 9; ++j) {          // 9*1024 = 9216 = BCAP coverage
        int idx = j * 1024 + tid;
        sp[j] = -1;
        if (idx < ne) {
            i32x2 e = bkt[base + idx];
            int col = e[0] & 0x00FFFFFF;
            int rl  = ((unsigned)e[0]) >> 24;
            int key = (rl << 5) | (col >> 12);         // chunk = col>>12 in [0,25)
            int sh  = (key & 1) << 4;
            int old = atomicAdd(&cntp[key >> 1], 1 << sh);  // LDS atomic, packed
            int s   = (old >> sh) & 0xFFFF;
            w0[j] = col; w1[j] = e[1];
            sp[j] = (key << 16) | s;                   // key 13b, slot 16b
        }
    }
    __syncthreads();
    // two-level exclusive scan over 8192 keys (8 keys = 4 packed ints / thread)
    int pv[4]; int s_t = 0;
#pragma unroll
    for (int k = 0; k < 4; ++k) {
        pv[k] = cntp[tid * 4 + k];
        s_t += (pv[k] & 0xFFFF) + ((unsigned)pv[k] >> 16);
    }
    ts[tid] = s_t;
    __syncthreads();
    for (int off = 1; off < 1024; off <<= 1) {         // H-S inclusive scan
        int v = (tid >= off) ? ts[tid - off] : 0;
        __syncthreads();
        ts[tid] += v;
        __syncthreads();
    }
    int run = ts[tid] - s_t;                           // exclusive thread base
#pragma unroll
    for (int k = 0; k < 4; ++k) {
        int key0 = tid * 8 + 2 * k;
        scn16[key0]     = (unsigned short)run;  run += pv[k] & 0xFFFF;
        scn16[key0 + 1] = (unsigned short)run;  run += (int)((unsigned)pv[k] >> 16);
    }
    __syncthreads();
    if (tid < 256) {
        int row = (b << 8) + tid;
        if (row < N_NODES) {
            int off0 = scn16[tid << 5];
            int off1 = (tid < 255) ? (int)scn16[(tid + 1) << 5] : ne;
            rowptr[row] = base + off0;
            cntout[row] = off1 - off0;
        }
    }
    __syncthreads();
#pragma unroll
    for (int j = 0; j < 9; ++j) {
        if (sp[j] >= 0) {
            int key = (int)(((unsigned)sp[j]) >> 16), s = sp[j] & 0xFFFF;
            i32x2 o; o[0] = w0[j]; o[1] = w1[j];
            bkt[base + (int)scn16[key] + s] = o;
        }
    }
}

// ---- pair-gather SpMM: 2 edges per instruction (half-wave split) ----
__global__ __launch_bounds__(256) void spmm_gather(
    const int* __restrict__ rowptr, const int* __restrict__ cntout,
    const i32x2* __restrict__ csr,
    const unsigned short* __restrict__ sb, float* __restrict__ out)
{
    int wave = (int)((blockIdx.x * 256u + threadIdx.x) >> 6);
    if (wave >= N_NODES) return;
    int lane = threadIdx.x & 63;
    int hi = lane >> 5;                                  // 0: edge A, 1: edge B
    const unsigned short* base = sb + (size_t)(lane & 31) * 8;   // 8 ch/lane

    int beg = rowptr[wave];
    int end = beg + cntout[wave];

    f32x4 a0 = {0.f,0.f,0.f,0.f}, b0 = {0.f,0.f,0.f,0.f};
    f32x4 a1 = {0.f,0.f,0.f,0.f}, b1 = {0.f,0.f,0.f,0.f};
    f32x4 a2 = {0.f,0.f,0.f,0.f}, b2 = {0.f,0.f,0.f,0.f};
    f32x4 a3 = {0.f,0.f,0.f,0.f}, b3 = {0.f,0.f,0.f,0.f};

#define PAIR(AA, BB, EE) do {                                        \
        i32x2 pa = __builtin_nontemporal_load(csr + (EE));           \
        i32x2 pb = __builtin_nontemporal_load(csr + (EE) + 1);       \
        int   col = hi ? pb[0] : pa[0];                              \
        float v   = __int_as_float(hi ? pb[1] : pa[1]);              \
        bf16x8 s = *(const bf16x8*)(base + ((size_t)col << 8));      \
        AA[0] += v * bf2f((unsigned short)s[0]);                     \
        AA[1] += v * bf2f((unsigned short)s[1]);                     \
        AA[2] += v * bf2f((unsigned short)s[2]);                     \
        AA[3] += v * bf2f((unsigned short)s[3]);                     \
        BB[0] += v * bf2f((unsigned short)s[4]);                     \
        BB[1] += v * bf2f((unsigned short)s[5]);                     \
        BB[2] += v * bf2f((unsigned short)s[6]);                     \
        BB[3] += v * bf2f((unsigned short)s[7]);                     \
    } while (0)

    int e = beg;
    for (; e + 8 <= end; e += 8) {
        PAIR(a0, b0, e);
        PAIR(a1, b1, e + 2);
        PAIR(a2, b2, e + 4);
        PAIR(a3, b3, e + 6);
    }
    for (; e + 2 <= end; e += 2) PAIR(a0, b0, e);
    if (e < end) {                                   // odd tail: hi half idle
        i32x2 pa = __builtin_nontemporal_load(csr + e);
        int   col = pa[0];
        float v   = hi ? 0.f : __int_as_float(pa[1]);
        bf16x8 s = *(const bf16x8*)(base + ((size_t)col << 8));
        a0[0] += v * bf2f((unsigned short)s[0]);
        a0[1] += v * bf2f((unsigned short)s[1]);
        a0[2] += v * bf2f((unsigned short)s[2]);
        a0[3] += v * bf2f((unsigned short)s[3]);
        b0[0] += v * bf2f((unsigned short)s[4]);
        b0[1] += v * bf2f((unsigned short)s[5]);
        b0[2] += v * bf2f((unsigned short)s[6]);
        b0[3] += v * bf2f((unsigned short)s[7]);
    }
#undef PAIR

    f32x4 A = (a0 + a1) + (a2 + a3);
    f32x4 B = (b0 + b1) + (b2 + b3);
#pragma unroll
    for (int j = 0; j < 4; ++j) {
        A[j] += __shfl_xor(A[j], 32);
        B[j] += __shfl_xor(B[j], 32);
    }
    if (lane < 32) {
        float* o = out + (size_t)wave * D + lane * 8;
        __builtin_nontemporal_store(A, (f32x4*)o);
        __builtin_nontemporal_store(B, (f32x4*)(o + 4));
    }
}

extern "C" void kernel_launch(void* const* d_in, const int* in_sizes, int n_in,
                              void* d_out, int out_size, void* d_ws, size_t ws_size,
                              hipStream_t stream) {
    const float* x    = (const float*)d_in[0];
    const float* W    = (const float*)d_in[1];
    const int*   erow = (const int*)d_in[2];
    const int*   ecol = (const int*)d_in[3];
    const float* eval = (const float*)d_in[4];
    float* out = (float*)d_out;

    // ---- workspace layout (bytes) ----
    char* ws = (char*)d_ws;
    unsigned short* wb     = (unsigned short*)(ws + 0);          // 131,072
    unsigned short* sb     = (unsigned short*)(ws + 131072);     // 51,200,000
    int*            bnext  = (int*)(ws + 51331072);              // 1,564 (4KB pad)
    int*            rowptr = (int*)(ws + 51335168);              // 400,000
    int*            cnt    = (int*)(ws + 51735168);              // 400,000
    i32x2*          bkt    = (i32x2*)(ws + 52135168);            // 28,827,648
    // total 80,962,816 bytes (~81 MB); csr aliases bkt (in-place regroup)

    prep<<<CVT_BLOCKS + 2, 256, 0, stream>>>(W, wb, bnext);

    gemm_part<<<3 * P1_BLOCKS, 256, 0, stream>>>(
        x, wb, sb, (const i32x4*)erow, (const i32x4*)ecol, (const f32x4*)eval,
        bnext, bkt);

    build_csr<<<NBKT, 1024, 0, stream>>>(bnext, bkt, rowptr, cnt);

    spmm_gather<<<N_NODES / 4, 256, 0, stream>>>(rowptr, cnt, bkt, sb, out);
}

// Round 5
// 565.555 us; speedup vs baseline: 1.0433x; 1.0433x over previous
//
#include <hip/hip_runtime.h>

#define N_NODES 100000
#define N_EDGES 3200000
#define D 256

#define NBKT 782           // row-buckets of 128 rows each (782*128 = 100096)
#define BCAP 4608          // entries per bucket; mean 4092, ~8 sigma margin
#define P1_BLOCKS 782      // 4096 edges per partition block
#define CVT_BLOCKS 64      // 65536 W elems / (256*4)

using bf16x8 = __attribute__((ext_vector_type(8))) short;
using f32x4  = __attribute__((ext_vector_type(4))) float;
using i32x4  = __attribute__((ext_vector_type(4))) int;
using i32x2  = __attribute__((ext_vector_type(2))) int;

__device__ inline float bf2f(unsigned short b) {
    union { unsigned u; float f; } v; v.u = ((unsigned)b) << 16; return v.f;
}
__device__ inline unsigned short f2bf(float f) {
    union { float f; unsigned u; } v; v.f = f;
    unsigned u = v.u;
    u += 0x7FFFu + ((u >> 16) & 1u);   // round-to-nearest-even
    return (unsigned short)(u >> 16);
}

// ---- prep: [0,64) convert W fp32->bf16; rest init bucket_next ----
__global__ __launch_bounds__(256) void prep(const float* __restrict__ W,
                                            unsigned short* __restrict__ wb,
                                            int* __restrict__ bucket_next) {
    int bid = blockIdx.x;
    if (bid < CVT_BLOCKS) {
        int i = (bid * 256 + threadIdx.x) * 4;
        float4 f = *(const float4*)(W + i);
        ushort4 o;
        o.x = f2bf(f.x); o.y = f2bf(f.y); o.z = f2bf(f.z); o.w = f2bf(f.w);
        *(ushort4*)(wb + i) = o;
    } else {
        int t = (bid - CVT_BLOCKS) * 256 + threadIdx.x;
        if (t < NBKT) bucket_next[t] = t * BCAP;
    }
}

// ---- fused: GEMM (MFMA) || edge partition into 128-row buckets ----
// Partition: per-edge ranking via LDS atomics (CU-local); ~782 global
// atomics per block for space reservation only (memory-side RMW wall
// measured at ~20/cycle device-wide; per-edge global atomics are fatal).
__global__ __launch_bounds__(256) void gemm_part(
    const float* __restrict__ x,            // [N_NODES, 256] fp32
    const unsigned short* __restrict__ wb,  // [256, 256] bf16
    unsigned short* __restrict__ sb,        // [N_NODES, 256] bf16 out
    const i32x4* __restrict__ erow4,
    const i32x4* __restrict__ ecol4,
    const f32x4* __restrict__ eval4,
    int* __restrict__ bucket_next,          // [NBKT], pre-set to b*BCAP
    i32x2* __restrict__ bkt)                // [NBKT*BCAP] partitioned edges
{
    __shared__ int h_cnt[NBKT];
    __shared__ int h_base[NBKT];
    int bid = blockIdx.x;
    int r3 = bid % 3, g3 = bid / 3;
    if (r3 == 0) {
        // ---------- partition role: p in [0, 782) ----------
        int p = g3;
        int tid = threadIdx.x;
        for (int i = tid; i < NBKT; i += 256) h_cnt[i] = 0;
        __syncthreads();
        int e0 = p * 4096;
        int jmax = (N_EDGES - e0) >> 10; if (jmax > 4) jmax = 4;
        int w0[4][4], w1[4][4], bs[4][4];
#pragma unroll
        for (int j = 0; j < 4; ++j) {
            if (j < jmax) {
                int q = p * 1024 + j * 256 + tid;          // i32x4 index
                i32x4 r4 = __builtin_nontemporal_load(erow4 + q);
                i32x4 c4 = __builtin_nontemporal_load(ecol4 + q);
                f32x4 v4 = __builtin_nontemporal_load(eval4 + q);
#pragma unroll
                for (int k = 0; k < 4; ++k) {
                    int row = r4[k];
                    int b   = row >> 7;
                    int rl  = row & 127;
                    int slot = atomicAdd(&h_cnt[b], 1);    // LDS atomic, returning
                    w0[j][k] = c4[k] | (rl << 24);
                    w1[j][k] = __float_as_int(v4[k]);
                    bs[j][k] = (b << 13) | slot;           // slot < 4096 fits 13b
                }
            }
        }
        __syncthreads();
        for (int i = tid; i < NBKT; i += 256)
            h_base[i] = atomicAdd(&bucket_next[i], h_cnt[i]);  // global reservation
        __syncthreads();
#pragma unroll
        for (int j = 0; j < 4; ++j) {
            if (j < jmax) {
#pragma unroll
                for (int k = 0; k < 4; ++k) {
                    int b    = bs[j][k] >> 13;
                    int slot = bs[j][k] & 8191;
                    int dst  = h_base[b] + slot;
                    if (dst < (b + 1) * BCAP) {            // ~8-sigma safety clamp
                        i32x2 o; o[0] = w0[j][k]; o[1] = w1[j][k];
                        bkt[dst] = o;
                    }
                }
            }
        }
        return;
    }
    // ---------- GEMM role: g = 2*g3 + (r3-1) in [0, 1564) ----------
    int g = 2 * g3 + (r3 - 1);
    int wave = g * 4 + (int)(threadIdx.x >> 6);
    int m0 = wave << 4;
    if (m0 >= N_NODES) return;
    int lane = threadIdx.x & 63;
    int quad = lane >> 4;
    int r16  = lane & 15;

    const f32x4* arow = (const f32x4*)(x + (size_t)(m0 + r16) * D + quad * 8);
    const unsigned short* bbase = wb + (size_t)r16 * D + quad * 8;

    f32x4 acc[16];
#pragma unroll
    for (int t = 0; t < 16; ++t) acc[t] = (f32x4){0.f, 0.f, 0.f, 0.f};

    for (int k0 = 0; k0 < D; k0 += 32) {
        f32x4 fa0 = __builtin_nontemporal_load(arow + (k0 >> 2));
        f32x4 fa1 = __builtin_nontemporal_load(arow + (k0 >> 2) + 1);
        bf16x8 a;
        a[0] = (short)f2bf(fa0[0]); a[1] = (short)f2bf(fa0[1]);
        a[2] = (short)f2bf(fa0[2]); a[3] = (short)f2bf(fa0[3]);
        a[4] = (short)f2bf(fa1[0]); a[5] = (short)f2bf(fa1[1]);
        a[6] = (short)f2bf(fa1[2]); a[7] = (short)f2bf(fa1[3]);
#pragma unroll
        for (int t = 0; t < 16; ++t) {
            bf16x8 b = *(const bf16x8*)(bbase + (size_t)t * 16 * D + k0);
            // swapped operands: lane holds 4 consecutive channels of one node
            acc[t] = __builtin_amdgcn_mfma_f32_16x16x32_bf16(b, a, acc[t], 0, 0, 0);
        }
    }

#pragma unroll
    for (int t = 0; t < 16; ++t) {
        ushort4 o;
        o.x = f2bf(acc[t][0]); o.y = f2bf(acc[t][1]);
        o.z = f2bf(acc[t][2]); o.w = f2bf(acc[t][3]);
        *(ushort4*)(sb + (size_t)(m0 + r16) * D + t * 16 + quad * 4) = o;
    }
}

// ---- fused group + gather: one 512-thread block per 128-row bucket ----
// Count (LDS atomics) -> 128-key scan -> place grouped edges in LDS ->
// pair-gather SpMM straight from LDS. Eliminates build_csr's 51 MB global
// round-trip, the spmm csr loads, and one dispatch. 38 KB LDS -> 4 blk/CU.
__global__ __launch_bounds__(512) void csr_spmm(
    const int* __restrict__ bucket_next,
    const i32x2* __restrict__ bkt,
    const unsigned short* __restrict__ sb, float* __restrict__ out)
{
    __shared__ int2 lds_e[BCAP];        // 36,864 B
    __shared__ int cnt[128], scn[128], cur[128];
    int b = blockIdx.x, tid = threadIdx.x;
    int base = b * BCAP;
    int ne = bucket_next[b] - base; if (ne > BCAP) ne = BCAP;

    if (tid < 128) cnt[tid] = 0;
    __syncthreads();
    // pass 1: count rows (bucket region is 37 KB -> stays L1/L2-hot for pass 2)
    for (int idx = tid; idx < ne; idx += 512) {
        i32x2 e = bkt[base + idx];
        atomicAdd(&cnt[((unsigned)e[0]) >> 24], 1);
    }
    __syncthreads();
    if (tid < 128) scn[tid] = cnt[tid];
    __syncthreads();
    for (int off = 1; off < 128; off <<= 1) {      // Hillis-Steele over 128
        int v = 0;
        if (tid < 128 && tid >= off) v = scn[tid - off];
        __syncthreads();
        if (tid < 128) scn[tid] += v;
        __syncthreads();
    }
    if (tid < 128) { int ex = scn[tid] - cnt[tid]; scn[tid] = ex; cur[tid] = ex; }
    __syncthreads();
    // pass 2: place grouped into LDS
    for (int idx = tid; idx < ne; idx += 512) {
        i32x2 e = bkt[base + idx];
        int rl  = ((unsigned)e[0]) >> 24;
        int pos = atomicAdd(&cur[rl], 1);          // LDS atomic, returning
        lds_e[pos] = make_int2(e[0] & 0x00FFFFFF, e[1]);
    }
    __syncthreads();

    // ---- pair-gather SpMM: 8 waves x 16 rows, edges from LDS ----
    int wid = tid >> 6, lane = tid & 63, hi = lane >> 5;
    const unsigned short* basep = sb + (size_t)(lane & 31) * 8;  // 8 ch/lane

#define PAIR(AA, BB, EE) do {                                        \
        int2 pa = lds_e[EE];                                         \
        int2 pb = lds_e[(EE) + 1];                                   \
        int   col = hi ? pb.x : pa.x;                                \
        float v   = __int_as_float(hi ? pb.y : pa.y);                \
        bf16x8 s = *(const bf16x8*)(basep + ((size_t)col << 8));     \
        AA[0] += v * bf2f((unsigned short)s[0]);                     \
        AA[1] += v * bf2f((unsigned short)s[1]);                     \
        AA[2] += v * bf2f((unsigned short)s[2]);                     \
        AA[3] += v * bf2f((unsigned short)s[3]);                     \
        BB[0] += v * bf2f((unsigned short)s[4]);                     \
        BB[1] += v * bf2f((unsigned short)s[5]);                     \
        BB[2] += v * bf2f((unsigned short)s[6]);                     \
        BB[3] += v * bf2f((unsigned short)s[7]);                     \
    } while (0)

    for (int r = 0; r < 16; ++r) {
        int rl  = wid * 16 + r;
        int row = (b << 7) + rl;
        if (row >= N_NODES) break;
        int e   = scn[rl];
        int end = cur[rl];                // == scn+cnt after placement

        f32x4 a0 = {0.f,0.f,0.f,0.f}, b0 = {0.f,0.f,0.f,0.f};
        f32x4 a1 = {0.f,0.f,0.f,0.f}, b1 = {0.f,0.f,0.f,0.f};
        f32x4 a2 = {0.f,0.f,0.f,0.f}, b2 = {0.f,0.f,0.f,0.f};
        f32x4 a3 = {0.f,0.f,0.f,0.f}, b3 = {0.f,0.f,0.f,0.f};

        for (; e + 8 <= end; e += 8) {
            PAIR(a0, b0, e);
            PAIR(a1, b1, e + 2);
            PAIR(a2, b2, e + 4);
            PAIR(a3, b3, e + 6);
        }
        for (; e + 2 <= end; e += 2) PAIR(a0, b0, e);
        if (e < end) {                               // odd tail: hi half idle
            int2 pa = lds_e[e];
            int   col = pa.x;
            float v   = hi ? 0.f : __int_as_float(pa.y);
            bf16x8 s = *(const bf16x8*)(basep + ((size_t)col << 8));
            a0[0] += v * bf2f((unsigned short)s[0]);
            a0[1] += v * bf2f((unsigned short)s[1]);
            a0[2] += v * bf2f((unsigned short)s[2]);
            a0[3] += v * bf2f((unsigned short)s[3]);
            b0[0] += v * bf2f((unsigned short)s[4]);
            b0[1] += v * bf2f((unsigned short)s[5]);
            b0[2] += v * bf2f((unsigned short)s[6]);
            b0[3] += v * bf2f((unsigned short)s[7]);
        }

        f32x4 A = (a0 + a1) + (a2 + a3);
        f32x4 B = (b0 + b1) + (b2 + b3);
#pragma unroll
        for (int j = 0; j < 4; ++j) {
            A[j] += __shfl_xor(A[j], 32);
            B[j] += __shfl_xor(B[j], 32);
        }
        if (lane < 32) {
            float* o = out + (size_t)row * D + lane * 8;
            __builtin_nontemporal_store(A, (f32x4*)o);
            __builtin_nontemporal_store(B, (f32x4*)(o + 4));
        }
    }
#undef PAIR
}

extern "C" void kernel_launch(void* const* d_in, const int* in_sizes, int n_in,
                              void* d_out, int out_size, void* d_ws, size_t ws_size,
                              hipStream_t stream) {
    const float* x    = (const float*)d_in[0];
    const float* W    = (const float*)d_in[1];
    const int*   erow = (const int*)d_in[2];
    const int*   ecol = (const int*)d_in[3];
    const float* eval = (const float*)d_in[4];
    float* out = (float*)d_out;

    // ---- workspace layout (bytes) ----
    char* ws = (char*)d_ws;
    unsigned short* wb    = (unsigned short*)(ws + 0);          // 131,072
    unsigned short* sb    = (unsigned short*)(ws + 131072);     // 51,200,000
    int*            bnext = (int*)(ws + 51331072);              // 3,128 (4KB pad)
    i32x2*          bkt   = (i32x2*)(ws + 51335168);            // 28,827,648
    // total 80,162,816 bytes (~80 MB)

    prep<<<CVT_BLOCKS + 4, 256, 0, stream>>>(W, wb, bnext);

    gemm_part<<<3 * P1_BLOCKS, 256, 0, stream>>>(
        x, wb, sb, (const i32x4*)erow, (const i32x4*)ecol, (const f32x4*)eval,
        bnext, bkt);

    csr_spmm<<<NBKT, 512, 0, stream>>>(bnext, bkt, sb, out);
}